// Round 1
// baseline (251.785 us; speedup 1.0000x reference)
//
#include <hip/hip_runtime.h>

#define EPS 1e-4f
constexpr int N_DIM = 1024;
constexpr int M_DIM = 1024;

// ---------------------------------------------------------------------------
// col update: c[b][m] = 1 / sum_{n < R} r[b][n] * (s[b][n][m] + EPS)
// FIRST=true treats r == 1 (iteration 0).
// grid: (M/64, B), block: 256 threads = 64 cols x 4 row-groups.
// ---------------------------------------------------------------------------
template <bool FIRST>
__global__ void sinkhorn_colupd(const float* __restrict__ s,
                                const int* __restrict__ nrows,
                                const int* __restrict__ ncols,
                                const float* __restrict__ r,
                                float* __restrict__ c) {
    const int b = blockIdx.y;
    const int R = nrows[b];
    const int C = ncols[b];
    const int m0 = blockIdx.x * 64;
    if (m0 >= C) return;                     // entire tile outside valid cols

    const int col = threadIdx.x & 63;        // 0..63
    const int rg  = threadIdx.x >> 6;        // 0..3 (wave id)
    const int m   = m0 + col;

    const float* __restrict__ sb = s + (size_t)b * N_DIM * M_DIM;
    const float* __restrict__ rb = r + b * N_DIM;

    float sum = 0.f;
#pragma unroll 4
    for (int n = rg; n < R; n += 4) {
        float v = sb[(size_t)n * M_DIM + m] + EPS;
        sum += FIRST ? v : rb[n] * v;
    }

    __shared__ float red[4][64];
    red[rg][col] = sum;
    __syncthreads();
    if (rg == 0 && m < C) {
        float t = red[0][col] + red[1][col] + red[2][col] + red[3][col];
        c[b * M_DIM + m] = (t == 0.f) ? 1.f : 1.f / t;
    }
}

// ---------------------------------------------------------------------------
// row update: r[b][n] = 1 / sum_{m < C} c[b][m] * (s[b][n][m] + EPS)
// grid: (N/4, B), block: 256 threads = 4 waves, one row per wave.
// ---------------------------------------------------------------------------
__global__ void sinkhorn_rowupd(const float* __restrict__ s,
                                const int* __restrict__ nrows,
                                const int* __restrict__ ncols,
                                const float* __restrict__ c,
                                float* __restrict__ r) {
    const int b = blockIdx.y;
    const int R = nrows[b];
    const int C = ncols[b];
    const int n = blockIdx.x * 4 + (threadIdx.x >> 6);
    if (n >= R) return;
    const int lane = threadIdx.x & 63;

    const float* __restrict__ srow = s + ((size_t)b * N_DIM + n) * M_DIM;
    const float* __restrict__ cb   = c + b * M_DIM;

    float sum = 0.f;
    const int C4 = C >> 2;                         // full float4 groups
    const float4* __restrict__ s4 = (const float4*)srow;
    const float4* __restrict__ c4 = (const float4*)cb;
    for (int i = lane; i < C4; i += 64) {
        float4 v = s4[i];
        float4 cc = c4[i];
        sum += (v.x + EPS) * cc.x + (v.y + EPS) * cc.y +
               (v.z + EPS) * cc.z + (v.w + EPS) * cc.w;
    }
    for (int m = C4 * 4 + lane; m < C; m += 64)    // tail (C not multiple of 4)
        sum += (srow[m] + EPS) * cb[m];

#pragma unroll
    for (int off = 32; off; off >>= 1) sum += __shfl_down(sum, off);
    if (lane == 0)
        r[b * N_DIM + n] = (sum == 0.f) ? 1.f : 1.f / sum;
}

// ---------------------------------------------------------------------------
// finalize: out[b][n][m] = (n<R && m<C) ? (s+EPS)*r[n]*c[m] : 0
// grid: (N, B), block: 256 threads, one float4 per thread (256*4 == M).
// ---------------------------------------------------------------------------
__global__ void sinkhorn_finalize(const float* __restrict__ s,
                                  const int* __restrict__ nrows,
                                  const int* __restrict__ ncols,
                                  const float* __restrict__ r,
                                  const float* __restrict__ c,
                                  float* __restrict__ out) {
    const int n = blockIdx.x;
    const int b = blockIdx.y;
    const int R = nrows[b];
    const int C = ncols[b];
    const size_t base = ((size_t)b * N_DIM + n) * M_DIM;
    const int m = threadIdx.x * 4;

    float4 o = make_float4(0.f, 0.f, 0.f, 0.f);
    if (n < R && m < C) {
        const float rn = r[b * N_DIM + n];
        float4 v  = *(const float4*)(s + base + m);
        float4 cc = *(const float4*)(c + b * M_DIM + m);
        o.x = (m + 0 < C) ? (v.x + EPS) * rn * cc.x : 0.f;
        o.y = (m + 1 < C) ? (v.y + EPS) * rn * cc.y : 0.f;
        o.z = (m + 2 < C) ? (v.z + EPS) * rn * cc.z : 0.f;
        o.w = (m + 3 < C) ? (v.w + EPS) * rn * cc.w : 0.f;
    }
    *(float4*)(out + base + m) = o;
}

extern "C" void kernel_launch(void* const* d_in, const int* in_sizes, int n_in,
                              void* d_out, int out_size, void* d_ws, size_t ws_size,
                              hipStream_t stream) {
    const float* s     = (const float*)d_in[0];
    const int*   nrows = (const int*)d_in[1];
    const int*   ncols = (const int*)d_in[2];
    float*       out   = (float*)d_out;
    const int B = in_sizes[1];

    float* r = (float*)d_ws;                 // B * N floats
    float* c = r + (size_t)B * N_DIM;        // B * M floats

    dim3 colGrid(M_DIM / 64, B);
    dim3 rowGrid(N_DIM / 4, B);

    // i=0: column normalization with implicit r == 1
    sinkhorn_colupd<true><<<colGrid, 256, 0, stream>>>(s, nrows, ncols, r, c);
    sinkhorn_rowupd<<<rowGrid, 256, 0, stream>>>(s, nrows, ncols, c, r);   // i=1
    for (int it = 0; it < 4; ++it) {         // i=2..9
        sinkhorn_colupd<false><<<colGrid, 256, 0, stream>>>(s, nrows, ncols, r, c);
        sinkhorn_rowupd<<<rowGrid, 256, 0, stream>>>(s, nrows, ncols, c, r);
    }

    sinkhorn_finalize<<<dim3(N_DIM, B), 256, 0, stream>>>(s, nrows, ncols, r, c, out);
}